// Round 10
// baseline (976.299 us; speedup 1.0000x reference)
//
#include <hip/hip_runtime.h>
#include <cstddef>
#include <cstdint>

#define SEQ    2048
#define DIM    64
#define NHEAD  32
#define BM     128          // kfsplit rows per block
#define STRIDE 2052         // strip row stride in floats (2048 + 4 pad -> 2-way banks)
#define LOG2E  1.44269504088896340736f

typedef __attribute__((ext_vector_type(8))) short short8v;  // 8 bf16 = one MFMA A/B frag
typedef __attribute__((ext_vector_type(4))) float f32x4;    // MFMA accumulator

__device__ __forceinline__ float fexp2(float x) { return __builtin_amdgcn_exp2f(x); }

// f32 -> bf16 round-to-nearest-even
__device__ __forceinline__ unsigned short f2bf(float x) {
    union { float f; unsigned u; } v; v.f = x;
    unsigned r = v.u + 0x7FFFu + ((v.u >> 16) & 1u);
    return (unsigned short)(r >> 16);
}
__device__ __forceinline__ float bf2f(unsigned short h) {
    union { unsigned u; float f; } v; v.u = ((unsigned)h) << 16;
    return v.f;
}

// ---------------------------------------------------------------------------
// K1 (unchanged): kf = relu(k @ W^T) f32, split kf = kh + kl (bf16 pair),
// layout [head][s][f].
// ---------------------------------------------------------------------------
__global__ __launch_bounds__(256) void kfsplit_kernel(const float* __restrict__ kin,
                                                      const float* __restrict__ W,
                                                      unsigned short* __restrict__ khg,
                                                      unsigned short* __restrict__ klg)
{
    __shared__ __align__(16) float Ws[64 * 68];
    const int tid  = threadIdx.x;
    const int head = blockIdx.x >> 4;
    const int r0   = (blockIdx.x & 15) * BM;

    {
        const int f = tid >> 2, cc = (tid & 3) * 16;
        const float* gw = W + f * DIM + cc;
        #pragma unroll
        for (int kk = 0; kk < 4; ++kk)
            *reinterpret_cast<float4*>(&Ws[f * 68 + cc + kk * 4]) =
                *reinterpret_cast<const float4*>(gw + kk * 4);
    }
    __syncthreads();

    const int lane = tid & 63;
    const int wid  = tid >> 6;
    const float* kb = kin + ((size_t)head * SEQ + r0) * DIM;

    float acc0[16], acc1[16];
    #pragma unroll
    for (int j = 0; j < 16; ++j) { acc0[j] = 0.f; acc1[j] = 0.f; }

    for (int d4 = 0; d4 < 16; ++d4) {
        const float4 x0 = *reinterpret_cast<const float4*>(kb + (size_t)lane * DIM + d4 * 4);
        const float4 x1 = *reinterpret_cast<const float4*>(kb + (size_t)(64 + lane) * DIM + d4 * 4);
        #pragma unroll
        for (int j = 0; j < 16; ++j) {
            const float4 w4 = *reinterpret_cast<const float4*>(&Ws[(wid * 16 + j) * 68 + d4 * 4]);
            acc0[j] = fmaf(x0.x, w4.x, fmaf(x0.y, w4.y, fmaf(x0.z, w4.z, fmaf(x0.w, w4.w, acc0[j]))));
            acc1[j] = fmaf(x1.x, w4.x, fmaf(x1.y, w4.y, fmaf(x1.z, w4.z, fmaf(x1.w, w4.w, acc1[j]))));
        }
    }

#define SPLIT_ROW(ACC, ROWOFF)                                                          \
    do {                                                                                \
        unsigned hp[8], lp[8];                                                          \
        _Pragma("unroll")                                                               \
        for (int j2 = 0; j2 < 8; ++j2) {                                                \
            const float kf0 = fmaxf(ACC[2 * j2], 0.f);                                  \
            const float kf1 = fmaxf(ACC[2 * j2 + 1], 0.f);                              \
            const unsigned short h0 = f2bf(kf0), h1 = f2bf(kf1);                        \
            const unsigned short l0 = f2bf(kf0 - bf2f(h0));                             \
            const unsigned short l1 = f2bf(kf1 - bf2f(h1));                             \
            hp[j2] = (unsigned)h0 | ((unsigned)h1 << 16);                               \
            lp[j2] = (unsigned)l0 | ((unsigned)l1 << 16);                               \
        }                                                                               \
        unsigned short* dh = khg + ((size_t)head * SEQ + r0 + (ROWOFF)) * DIM + wid * 16; \
        unsigned short* dl = klg + ((size_t)head * SEQ + r0 + (ROWOFF)) * DIM + wid * 16; \
        uint4 a, b;                                                                     \
        a.x = hp[0]; a.y = hp[1]; a.z = hp[2]; a.w = hp[3];                             \
        b.x = hp[4]; b.y = hp[5]; b.z = hp[6]; b.w = hp[7];                             \
        *reinterpret_cast<uint4*>(dh) = a; *reinterpret_cast<uint4*>(dh + 8) = b;       \
        a.x = lp[0]; a.y = lp[1]; a.z = lp[2]; a.w = lp[3];                             \
        b.x = lp[4]; b.y = lp[5]; b.z = lp[6]; b.w = lp[7];                             \
        *reinterpret_cast<uint4*>(dl) = a; *reinterpret_cast<uint4*>(dl + 8) = b;       \
    } while (0)

    SPLIT_ROW(acc0, lane);
    SPLIT_ROW(acc1, 64 + lane);
#undef SPLIT_ROW
}

// ---------------------------------------------------------------------------
// K2 v4: single-pass row-strip kernel. Block = 16 q-rows x all 2048 kf-cols.
//  - scores (exp2 domain, log2e folded into qf) -> f32 LDS strip [16][2052]
//  - A-operands (kh/kl) read from global (L2-hot) with 2-band reg pipeline
//  - per-wave full-row softmax reduce (no cross-block/cross-wave merges)
//  - writes: 1KB contiguous per wave instruction, rows sequential
// 5 barriers total. LDS 131,328 B -> 1 block/CU.
// ---------------------------------------------------------------------------
__global__ __launch_bounds__(256, 1) void attn_kernel(const float* __restrict__ q,
                                                      const float* __restrict__ W,
                                                      const unsigned short* __restrict__ khg,
                                                      const unsigned short* __restrict__ klg,
                                                      float* __restrict__ out)
{
    __shared__ __align__(16) unsigned char lds_raw[16 * STRIDE * 4];   // 131,328 B
    float* strip = (float*)lds_raw;
    float* Ws    = (float*)lds_raw;            // phase 0 only  [64][68]
    float* qf    = (float*)(lds_raw + 32768);  // phase 0 only  [16][68]

    const int tid  = threadIdx.x;
    const int head = blockIdx.x >> 7;          // 128 row-blocks per head
    const int r0   = (blockIdx.x & 127) * 16;
    const int lane = tid & 63;
    const int wid  = tid >> 6;
    const int lr   = lane & 15, lh = lane >> 4;

    // ---- phase 0a: stage W ----
    {
        const int f = tid >> 2, cc = (tid & 3) * 16;
        const float* gw = W + f * DIM + cc;
        #pragma unroll
        for (int kk = 0; kk < 4; ++kk)
            *reinterpret_cast<float4*>(&Ws[f * 68 + cc + kk * 4]) =
                *reinterpret_cast<const float4*>(gw + kk * 4);
    }
    __syncthreads();

    // ---- phase 0b: qf[row][f] = relu(q . W^T) * log2e  (16 rows x 64 f) ----
    {
        const int row = tid & 15;
        const int fb  = (tid >> 4) * 4;        // 4 features per thread
        const float* qrow = q + ((size_t)head * SEQ + r0 + row) * DIM;
        float a[4] = {0.f, 0.f, 0.f, 0.f};
        for (int d4 = 0; d4 < 16; ++d4) {
            const float4 x = *reinterpret_cast<const float4*>(qrow + d4 * 4);
            const float xs[4] = {x.x, x.y, x.z, x.w};
            #pragma unroll
            for (int j = 0; j < 4; ++j)
                #pragma unroll
                for (int u = 0; u < 4; ++u)
                    a[j] = fmaf(xs[u], Ws[(fb + j) * 68 + d4 * 4 + u], a[j]);
        }
        #pragma unroll
        for (int j = 0; j < 4; ++j)
            qf[row * 68 + fb + j] = fmaxf(a[j] * LOG2E, 0.f);
    }
    __syncthreads();

    // ---- phase 0c: persistent B-frags (q side): col=lr=q-row, k=ks*32+lh*8+e
    short8v qh[2], ql[2];
    #pragma unroll
    for (int ks = 0; ks < 2; ++ks) {
        const float* src = &qf[lr * 68 + ks * 32 + lh * 8];
        short8v h, l;
        #pragma unroll
        for (int e = 0; e < 8; ++e) {
            const float x = src[e];
            const unsigned short hh = f2bf(x);
            h[e] = (short)hh;
            l[e] = (short)f2bf(x - bf2f(hh));
        }
        qh[ks] = h;
        ql[ks] = l;
    }
    __syncthreads();          // qf/Ws dead; strip writable

    // ---- score phase: wave wid covers cols wid*512 .. +511 in 8 bands of 64
    const unsigned short* khh = khg + (size_t)head * SEQ * DIM;
    const unsigned short* khl = klg + (size_t)head * SEQ * DIM;
    const int cb0 = wid * 512;

    short8v ah[2][4][2], al[2][4][2];   // [buf][cf][ks]
#define LOADB(BUF, B)                                                              \
    do {                                                                           \
        const int colb_ = cb0 + (B) * 64;                                          \
        _Pragma("unroll")                                                          \
        for (int cf = 0; cf < 4; ++cf) {                                           \
            const size_t ro_ = (size_t)(colb_ + cf * 16 + lr) * DIM + lh * 8;      \
            _Pragma("unroll")                                                      \
            for (int ks = 0; ks < 2; ++ks) {                                       \
                ah[BUF][cf][ks] = *reinterpret_cast<const short8v*>(khh + ro_ + ks * 32); \
                al[BUF][cf][ks] = *reinterpret_cast<const short8v*>(khl + ro_ + ks * 32); \
            }                                                                      \
        }                                                                          \
    } while (0)

    LOADB(0, 0);
    #pragma unroll
    for (int b = 0; b < 8; ++b) {
        const int cur = b & 1;
        if (b < 7) LOADB(cur ^ 1, b + 1);     // next band's loads fly under MFMA
        #pragma unroll
        for (int cf = 0; cf < 4; ++cf) {
            f32x4 a = {0.f, 0.f, 0.f, 0.f};
            a = __builtin_amdgcn_mfma_f32_16x16x32_bf16(ah[cur][cf][0], qh[0], a, 0, 0, 0);
            a = __builtin_amdgcn_mfma_f32_16x16x32_bf16(al[cur][cf][0], qh[0], a, 0, 0, 0);
            a = __builtin_amdgcn_mfma_f32_16x16x32_bf16(ah[cur][cf][0], ql[0], a, 0, 0, 0);
            a = __builtin_amdgcn_mfma_f32_16x16x32_bf16(ah[cur][cf][1], qh[1], a, 0, 0, 0);
            a = __builtin_amdgcn_mfma_f32_16x16x32_bf16(al[cur][cf][1], qh[1], a, 0, 0, 0);
            a = __builtin_amdgcn_mfma_f32_16x16x32_bf16(ah[cur][cf][1], ql[1], a, 0, 0, 0);
            // D: col=lr=q-row; reg j -> kf-col = band + cf*16 + lh*4 + j
            *reinterpret_cast<f32x4*>(&strip[lr * STRIDE + cb0 + b * 64 + cf * 16 + lh * 4]) = a;
        }
    }
#undef LOADB
    __syncthreads();          // full strip visible

    // ---- reduce + write: wave wid owns rows wid*4 .. +3 (full 2048 cols) ----
    #pragma unroll
    for (int rr = 0; rr < 4; ++rr) {
        const int row = wid * 4 + rr;
        const float* srow = strip + row * STRIDE;
        // row max (64 lanes x 32 values, linear conflict-free b128 reads)
        float mx = -INFINITY;
        #pragma unroll
        for (int i = 0; i < 8; ++i) {
            const float4 v = *reinterpret_cast<const float4*>(srow + i * 256 + lane * 4);
            mx = fmaxf(mx, fmaxf(fmaxf(v.x, v.y), fmaxf(v.z, v.w)));
        }
        #pragma unroll
        for (int s = 1; s < 64; s <<= 1) mx = fmaxf(mx, __shfl_xor(mx, s));
        // row sum
        float sm = 0.f;
        #pragma unroll
        for (int i = 0; i < 8; ++i) {
            const float4 v = *reinterpret_cast<const float4*>(srow + i * 256 + lane * 4);
            sm += fexp2(v.x - mx) + fexp2(v.y - mx) + fexp2(v.z - mx) + fexp2(v.w - mx);
        }
        #pragma unroll
        for (int s = 1; s < 64; s <<= 1) sm += __shfl_xor(sm, s);
        const float ri = 1.0f / sm;
        // write: 8 instrs x 1KB contiguous
        float* orow = out + ((size_t)head * SEQ + r0 + row) * SEQ;
        #pragma unroll
        for (int i = 0; i < 8; ++i) {
            const float4 v = *reinterpret_cast<const float4*>(srow + i * 256 + lane * 4);
            float4 o;
            o.x = fexp2(v.x - mx) * ri;
            o.y = fexp2(v.y - mx) * ri;
            o.z = fexp2(v.z - mx) * ri;
            o.w = fexp2(v.w - mx) * ri;
            *reinterpret_cast<float4*>(orow + i * 256 + lane * 4) = o;
        }
    }
}

// ---------------------------------------------------------------------------
// kh/kl (16 MiB total) go to d_ws when big enough; else they exactly fill the
// attn_output region of d_out (read by attn_kernel, then overwritten by the
// v copy — stream-ordered). attn_output == v (softmax rows sum to 1).
// ---------------------------------------------------------------------------
extern "C" void kernel_launch(void* const* d_in, const int* in_sizes, int n_in,
                              void* d_out, int out_size, void* d_ws, size_t ws_size,
                              hipStream_t stream)
{
    const float* q = (const float*)d_in[0];
    const float* k = (const float*)d_in[1];
    const float* v = (const float*)d_in[2];
    const float* W = (const float*)d_in[3];
    float* out = (float*)d_out;

    const size_t nkf = (size_t)NHEAD * SEQ * DIM;   // 4,194,304 elements
    unsigned short* kh;
    if (d_ws != nullptr && ws_size >= nkf * 4u) {
        kh = (unsigned short*)d_ws;
    } else {
        kh = (unsigned short*)out;
    }
    unsigned short* kl = kh + nkf;
    float* attn = out + nkf;

    kfsplit_kernel<<<NHEAD * (SEQ / BM), 256, 0, stream>>>(k, W, kh, kl);
    attn_kernel<<<NHEAD * 128, 256, 0, stream>>>(q, W, kh, kl, attn);

    hipMemcpyAsync((void*)out, (const void*)v, nkf * sizeof(float),
                   hipMemcpyDeviceToDevice, stream);
}